// Round 7
// baseline (812.311 us; speedup 1.0000x reference)
//
#include <hip/hip_runtime.h>
#include <hip/hip_bf16.h>
#include <math.h>

#define NNODES 20000
#define NPAD   20480   // 160 * 128 (160 bm strips -> 20 per XCD)
#define NBM    160
#define NEDGES 320000
#define HEADS  4
#define DDIM   256
#define MCOLS  1024   // H*D

typedef __attribute__((ext_vector_type(8))) short short8;
typedef __attribute__((ext_vector_type(4))) float f32x4;

// bf16 helpers (bit-level, RNE)
__device__ __forceinline__ unsigned short f2bf(float f) {
  unsigned u = __float_as_uint(f);
  unsigned r = (u + 0x7fffu + ((u >> 16) & 1u)) >> 16;
  return (unsigned short)r;
}
__device__ __forceinline__ float bf2f(unsigned short h) {
  return __uint_as_float(((unsigned)h) << 16);
}

__device__ __forceinline__ void async_ld16(void* lds, const void* g) {
  __builtin_amdgcn_global_load_lds(
      (const __attribute__((address_space(1))) unsigned int*)g,
      (__attribute__((address_space(3))) unsigned int*)lds, 16, 0, 0);
}

// ---------------- CSR build (by dst) ----------------
__global__ void k_zero(int* deg, int n) {
  int i = blockIdx.x*blockDim.x + threadIdx.x;
  if (i < n) deg[i] = 0;
}
__global__ void k_hist(const int* __restrict__ dst, int* deg, int e) {
  int i = blockIdx.x*blockDim.x + threadIdx.x;
  if (i < e) atomicAdd(&deg[dst[i]], 1);
}
__global__ void k_scan(const int* __restrict__ deg, int* row_ptr, int* cursor) {
  __shared__ int sm[1024];
  int t = threadIdx.x;
  const int CH = 20;
  int base = t*CH;
  int s = 0;
  #pragma unroll
  for (int i = 0; i < CH; ++i) { int idx = base+i; if (idx < NNODES) s += deg[idx]; }
  int val = s;
  sm[t] = s; __syncthreads();
  for (int off = 1; off < 1024; off <<= 1) {
    int add = (t >= off) ? sm[t-off] : 0;
    __syncthreads();
    val += add; sm[t] = val;
    __syncthreads();
  }
  int run = val - s;
  for (int i = 0; i < CH; ++i) {
    int idx = base+i;
    if (idx < NNODES) { row_ptr[idx] = run; cursor[idx] = run; run += deg[idx]; }
  }
  if (t == 0) row_ptr[NNODES] = NEDGES;
}
__global__ void k_fill(const int* __restrict__ src, const int* __restrict__ dst,
                       int* cursor, int* srcs_sorted, int* dsts_sorted, int e) {
  int i = blockIdx.x*blockDim.x + threadIdx.x;
  if (i < e) {
    int d = dst[i];
    int pos = atomicAdd(&cursor[d], 1);
    srcs_sorted[pos] = src[i];
    dsts_sorted[pos] = d;
  }
}

// ---------------- per-edge softmax weights: w[i,h]=exp(leaky(el[src]+er[dst])) ----
__global__ void k_wgt(const float* __restrict__ el, const float* __restrict__ er,
                      const int* __restrict__ srcs, const int* __restrict__ dsts,
                      float* __restrict__ w, int e4) {
  int i = blockIdx.x*blockDim.x + threadIdx.x;
  if (i >= e4) return;
  int pos = i >> 2, h = i & 3;
  float v = el[srcs[pos]*HEADS + h] + er[dsts[pos]*HEADS + h];
  v = v >= 0.f ? v : 0.2f*v;
  w[i] = __expf(v);
}

// ---------------- fold: F[k,h] = sum_d W[k, h*D+d] * v[h,d] ----------------
__global__ void k_fold(const float* __restrict__ W, const float* __restrict__ v,
                       float* __restrict__ F, int K) {
  int wave = threadIdx.x >> 6, lane = threadIdx.x & 63;
  int p = blockIdx.x*4 + wave;
  if (p >= K*HEADS) return;
  int k = p >> 2, h = p & 3;
  const float4 wv = *(const float4*)&W[(size_t)k*MCOLS + h*DDIM + lane*4];
  const float4 av = *(const float4*)&v[h*DDIM + lane*4];
  float s = wv.x*av.x + wv.y*av.y + wv.z*av.z + wv.w*av.w;
  for (int off = 32; off; off >>= 1) s += __shfl_xor(s, off);
  if (lane == 0) F[k*HEADS + h] = s;
}

// ---------------- split-bf16 conversion: A (row-major, padded) ----------------
__global__ void k_cvt_a(const float* __restrict__ x, unsigned short* __restrict__ hi,
                        unsigned short* __restrict__ lo, int total, int total_pad) {
  int i = blockIdx.x*blockDim.x + threadIdx.x;
  int idx = i*4;
  if (idx >= total_pad) return;
  float4 v = (idx < total) ? *(const float4*)&x[idx] : make_float4(0.f,0.f,0.f,0.f);
  ushort4 h, l;
  h.x = f2bf(v.x); l.x = f2bf(v.x - bf2f(h.x));
  h.y = f2bf(v.y); l.y = f2bf(v.y - bf2f(h.y));
  h.z = f2bf(v.z); l.z = f2bf(v.z - bf2f(h.z));
  h.w = f2bf(v.w); l.w = f2bf(v.w - bf2f(h.w));
  *(ushort4*)&hi[idx] = h;
  *(ushort4*)&lo[idx] = l;
}

// ---------------- bf16 transpose of W: [K][1024] -> [1024][K] (hi only) ----------
__global__ __launch_bounds__(256) void k_cvt_w(const float* __restrict__ W,
                                               unsigned short* __restrict__ Th, int K) {
  __shared__ float sm[32][33];
  int k0 = blockIdx.y*32, n0 = blockIdx.x*32;
  int t = threadIdx.x;
  int r = t >> 3, c4 = (t & 7)*4;
  *(float4*)&sm[r][c4] = *(const float4*)&W[(size_t)(k0 + r)*MCOLS + n0 + c4];
  __syncthreads();
  ushort4 h;
  h.x = f2bf(sm[c4+0][r]);
  h.y = f2bf(sm[c4+1][r]);
  h.z = f2bf(sm[c4+2][r]);
  h.w = f2bf(sm[c4+3][r]);
  *(ushort4*)&Th[(size_t)(n0 + r)*K + k0 + c4] = h;
}

// ---------------- el0/er0[n,h] = sum_k x[n,k]*{Wal0,Wred0}[k,h] ----------------
__global__ void k_eler0(const float* __restrict__ x, const float* __restrict__ Wal,
                        const float* __restrict__ Wred,
                        float* __restrict__ el, float* __restrict__ er) {
  int n = blockIdx.x;
  int h = threadIdx.x >> 6, lane = threadIdx.x & 63;
  float sl = 0.f, sr = 0.f;
  for (int k = lane; k < 512; k += 64) {
    float xv = x[(size_t)n*512 + k];
    sl = fmaf(xv, Wal[k*HEADS + h], sl);
    sr = fmaf(xv, Wred[k*HEADS + h], sr);
  }
  for (int off = 32; off; off >>= 1) { sl += __shfl_xor(sl, off); sr += __shfl_xor(sr, off); }
  if (lane == 0) { el[n*HEADS + h] = sl; er[n*HEADS + h] = sr; }
}

// ---------------- MFMA GEMM (split-2: Ah*Bh + Al*Bh), bf16 output ----------------
// XCD-aware swizzle (see r6): each XCD owns 20 exclusive bm strips.
__global__ __launch_bounds__(256, 3) void k_gemm_mfma(
    const unsigned short* __restrict__ Ah, const unsigned short* __restrict__ Al,
    const unsigned short* __restrict__ Bh,
    unsigned short* __restrict__ Fh, int K) {
  __shared__ short sAh[128*32], sAl[128*32], sBh[128*32];
  const int t = threadIdx.x;
  const int w = t >> 6, l = t & 63;
  const int b = blockIdx.x;
  const int xcd = b & 7, kk = b >> 3;
  const int bm = xcd*20 + (kk >> 3), bn = kk & 7;
  const int m0 = (w >> 1) * 64, n0 = (w & 1) * 64;

  f32x4 acc[4][4];
  #pragma unroll
  for (int i = 0; i < 4; ++i)
    #pragma unroll
    for (int j = 0; j < 4; ++j) acc[i][j] = (f32x4){0.f, 0.f, 0.f, 0.f};

  const int srow = t >> 2, koct = (t & 3) * 8;
  const size_t r64 = (size_t)64 * K;
  const unsigned short* gAh = Ah + (size_t)(bm*128 + srow)*K + koct;
  const unsigned short* gAl = Al + (size_t)(bm*128 + srow)*K + koct;
  const unsigned short* gBh = Bh + (size_t)(bn*128 + srow)*K + koct;
  char* lAh = (char*)sAh + w*1024;
  char* lAl = (char*)sAl + w*1024;
  char* lBh = (char*)sBh + w*1024;

  const int fr = l & 15, fq = l >> 4;

  for (int k0 = 0; k0 < K; k0 += 32) {
    async_ld16(lAh,        gAh + k0);
    async_ld16(lAh + 4096, gAh + k0 + r64);
    async_ld16(lAl,        gAl + k0);
    async_ld16(lAl + 4096, gAl + k0 + r64);
    async_ld16(lBh,        gBh + k0);
    async_ld16(lBh + 4096, gBh + k0 + r64);
    __syncthreads();

    short8 bhv[4];
    #pragma unroll
    for (int nt = 0; nt < 4; ++nt)
      bhv[nt] = *(const short8*)&sBh[(n0 + nt*16 + fr)*32 + fq*8];
    #pragma unroll
    for (int mt = 0; mt < 4; ++mt) {
      int off = (m0 + mt*16 + fr)*32 + fq*8;
      short8 ah = *(const short8*)&sAh[off];
      short8 al = *(const short8*)&sAl[off];
      #pragma unroll
      for (int nt = 0; nt < 4; ++nt) {
        acc[mt][nt] = __builtin_amdgcn_mfma_f32_16x16x32_bf16(ah, bhv[nt], acc[mt][nt], 0, 0, 0);
        acc[mt][nt] = __builtin_amdgcn_mfma_f32_16x16x32_bf16(al, bhv[nt], acc[mt][nt], 0, 0, 0);
      }
    }
    __syncthreads();
  }

  #pragma unroll
  for (int mt = 0; mt < 4; ++mt)
    #pragma unroll
    for (int nt = 0; nt < 4; ++nt) {
      size_t base = (size_t)(bm*128 + m0 + mt*16 + fq*4)*MCOLS + bn*128 + n0 + nt*16 + fr;
      Fh[base          ] = f2bf(acc[mt][nt][0]);
      Fh[base + MCOLS  ] = f2bf(acc[mt][nt][1]);
      Fh[base + 2*MCOLS] = f2bf(acc[mt][nt][2]);
      Fh[base + 3*MCOLS] = f2bf(acc[mt][nt][3]);
    }
}

// ---------------- fused aggregation (layers 0,1): bf16 gather, precomputed w ----
__global__ __launch_bounds__(256) void k_agg_f(
    const unsigned short* __restrict__ fsh, const float* __restrict__ wbuf,
    const int* __restrict__ row_ptr, const int* __restrict__ srcs,
    const float* __restrict__ bias,
    const float* __restrict__ WalN, const float* __restrict__ WredN,
    unsigned short* __restrict__ Ahi, unsigned short* __restrict__ Alo,
    float* __restrict__ el_next, float* __restrict__ er_next) {
  __shared__ float red_sm[HEADS][8];
  int n = blockIdx.x;
  int h = threadIdx.x >> 6, lane = threadIdx.x & 63;
  int k0 = h*DDIM + lane*4;
  if (n >= NNODES) {
    ushort4 z = {0,0,0,0};
    *(ushort4*)&Ahi[(size_t)n*MCOLS + k0] = z;
    *(ushort4*)&Alo[(size_t)n*MCOLS + k0] = z;
    return;
  }
  int beg = row_ptr[n], end = row_ptr[n+1];
  float den = 0.f;
  float4 acc = make_float4(0.f, 0.f, 0.f, 0.f);
  const char* fbyte = (const char*)fsh;
  const unsigned tb = (unsigned)(k0*2);   // thread-constant byte offset
  int i = beg;
  for (; i + 3 < end; i += 4) {
    float w0 = wbuf[(size_t)(i  )*HEADS + h];
    float w1 = wbuf[(size_t)(i+1)*HEADS + h];
    float w2 = wbuf[(size_t)(i+2)*HEADS + h];
    float w3 = wbuf[(size_t)(i+3)*HEADS + h];
    unsigned o0 = (unsigned)srcs[i  ]*2048u + tb;
    unsigned o1 = (unsigned)srcs[i+1]*2048u + tb;
    unsigned o2 = (unsigned)srcs[i+2]*2048u + tb;
    unsigned o3 = (unsigned)srcs[i+3]*2048u + tb;
    const ushort4 u0 = *(const ushort4*)(fbyte + o0);
    const ushort4 u1 = *(const ushort4*)(fbyte + o1);
    const ushort4 u2 = *(const ushort4*)(fbyte + o2);
    const ushort4 u3 = *(const ushort4*)(fbyte + o3);
    den += (w0 + w1) + (w2 + w3);
    acc.x = fmaf(w0, bf2f(u0.x), fmaf(w1, bf2f(u1.x), fmaf(w2, bf2f(u2.x), fmaf(w3, bf2f(u3.x), acc.x))));
    acc.y = fmaf(w0, bf2f(u0.y), fmaf(w1, bf2f(u1.y), fmaf(w2, bf2f(u2.y), fmaf(w3, bf2f(u3.y), acc.y))));
    acc.z = fmaf(w0, bf2f(u0.z), fmaf(w1, bf2f(u1.z), fmaf(w2, bf2f(u2.z), fmaf(w3, bf2f(u3.z), acc.z))));
    acc.w = fmaf(w0, bf2f(u0.w), fmaf(w1, bf2f(u1.w), fmaf(w2, bf2f(u2.w), fmaf(w3, bf2f(u3.w), acc.w))));
  }
  for (; i < end; ++i) {
    float wgt = wbuf[(size_t)i*HEADS + h];
    unsigned o = (unsigned)srcs[i]*2048u + tb;
    const ushort4 u = *(const ushort4*)(fbyte + o);
    den += wgt;
    acc.x = fmaf(wgt, bf2f(u.x), acc.x);
    acc.y = fmaf(wgt, bf2f(u.y), acc.y);
    acc.z = fmaf(wgt, bf2f(u.z), acc.z);
    acc.w = fmaf(wgt, bf2f(u.w), acc.w);
  }
  float inv = den > 0.f ? 1.f/den : 0.f;
  const float4 bv = *(const float4*)&bias[k0];
  float4 o;
  o.x = fmaxf(acc.x*inv + bv.x, 0.f);
  o.y = fmaxf(acc.y*inv + bv.y, 0.f);
  o.z = fmaxf(acc.z*inv + bv.z, 0.f);
  o.w = fmaxf(acc.w*inv + bv.w, 0.f);
  ushort4 hv, lv;
  hv.x = f2bf(o.x); lv.x = f2bf(o.x - bf2f(hv.x));
  hv.y = f2bf(o.y); lv.y = f2bf(o.y - bf2f(hv.y));
  hv.z = f2bf(o.z); lv.z = f2bf(o.z - bf2f(hv.z));
  hv.w = f2bf(o.w); lv.w = f2bf(o.w - bf2f(hv.w));
  *(ushort4*)&Ahi[(size_t)n*MCOLS + k0] = hv;
  *(ushort4*)&Alo[(size_t)n*MCOLS + k0] = lv;
  const float4 a0 = *(const float4*)&WalN[(k0+0)*HEADS];
  const float4 a1 = *(const float4*)&WalN[(k0+1)*HEADS];
  const float4 a2 = *(const float4*)&WalN[(k0+2)*HEADS];
  const float4 a3 = *(const float4*)&WalN[(k0+3)*HEADS];
  const float4 q0 = *(const float4*)&WredN[(k0+0)*HEADS];
  const float4 q1 = *(const float4*)&WredN[(k0+1)*HEADS];
  const float4 q2 = *(const float4*)&WredN[(k0+2)*HEADS];
  const float4 q3 = *(const float4*)&WredN[(k0+3)*HEADS];
  float p[8];
  p[0] = o.x*a0.x + o.y*a1.x + o.z*a2.x + o.w*a3.x;
  p[1] = o.x*a0.y + o.y*a1.y + o.z*a2.y + o.w*a3.y;
  p[2] = o.x*a0.z + o.y*a1.z + o.z*a2.z + o.w*a3.z;
  p[3] = o.x*a0.w + o.y*a1.w + o.z*a2.w + o.w*a3.w;
  p[4] = o.x*q0.x + o.y*q1.x + o.z*q2.x + o.w*q3.x;
  p[5] = o.x*q0.y + o.y*q1.y + o.z*q2.y + o.w*q3.y;
  p[6] = o.x*q0.z + o.y*q1.z + o.z*q2.z + o.w*q3.z;
  p[7] = o.x*q0.w + o.y*q1.w + o.z*q2.w + o.w*q3.w;
  for (int off = 32; off; off >>= 1)
    #pragma unroll
    for (int j = 0; j < 8; ++j) p[j] += __shfl_xor(p[j], off);
  if (lane == 0)
    #pragma unroll
    for (int j = 0; j < 8; ++j) red_sm[h][j] = p[j];
  __syncthreads();
  if (threadIdx.x < 8) {
    int t = threadIdx.x;
    float v = (red_sm[0][t] + red_sm[1][t]) + (red_sm[2][t] + red_sm[3][t]);
    if (t < 4) el_next[n*HEADS + t] = v;
    else       er_next[n*HEADS + (t-4)] = v;
  }
}

// ---------------- final aggregation (layer 2): bf16 gather, mean over heads ------
__global__ __launch_bounds__(256) void k_agg_out(
    const unsigned short* __restrict__ fsh, const float* __restrict__ wbuf,
    const int* __restrict__ row_ptr, const int* __restrict__ srcs,
    const float* __restrict__ bias, float* __restrict__ out) {
  __shared__ float sm[HEADS*DDIM];
  int n = blockIdx.x;
  int h = threadIdx.x >> 6, lane = threadIdx.x & 63;
  int beg = row_ptr[n], end = row_ptr[n+1];
  float den = 0.f;
  float4 acc = make_float4(0.f, 0.f, 0.f, 0.f);
  const char* fbyte = (const char*)fsh;
  const unsigned tb = (unsigned)((h*DDIM + lane*4)*2);
  int i = beg;
  for (; i + 3 < end; i += 4) {
    float w0 = wbuf[(size_t)(i  )*HEADS + h];
    float w1 = wbuf[(size_t)(i+1)*HEADS + h];
    float w2 = wbuf[(size_t)(i+2)*HEADS + h];
    float w3 = wbuf[(size_t)(i+3)*HEADS + h];
    unsigned o0 = (unsigned)srcs[i  ]*2048u + tb;
    unsigned o1 = (unsigned)srcs[i+1]*2048u + tb;
    unsigned o2 = (unsigned)srcs[i+2]*2048u + tb;
    unsigned o3 = (unsigned)srcs[i+3]*2048u + tb;
    const ushort4 u0 = *(const ushort4*)(fbyte + o0);
    const ushort4 u1 = *(const ushort4*)(fbyte + o1);
    const ushort4 u2 = *(const ushort4*)(fbyte + o2);
    const ushort4 u3 = *(const ushort4*)(fbyte + o3);
    den += (w0 + w1) + (w2 + w3);
    acc.x = fmaf(w0, bf2f(u0.x), fmaf(w1, bf2f(u1.x), fmaf(w2, bf2f(u2.x), fmaf(w3, bf2f(u3.x), acc.x))));
    acc.y = fmaf(w0, bf2f(u0.y), fmaf(w1, bf2f(u1.y), fmaf(w2, bf2f(u2.y), fmaf(w3, bf2f(u3.y), acc.y))));
    acc.z = fmaf(w0, bf2f(u0.z), fmaf(w1, bf2f(u1.z), fmaf(w2, bf2f(u2.z), fmaf(w3, bf2f(u3.z), acc.z))));
    acc.w = fmaf(w0, bf2f(u0.w), fmaf(w1, bf2f(u1.w), fmaf(w2, bf2f(u2.w), fmaf(w3, bf2f(u3.w), acc.w))));
  }
  for (; i < end; ++i) {
    float wgt = wbuf[(size_t)i*HEADS + h];
    unsigned o = (unsigned)srcs[i]*2048u + tb;
    const ushort4 u = *(const ushort4*)(fbyte + o);
    den += wgt;
    acc.x = fmaf(wgt, bf2f(u.x), acc.x);
    acc.y = fmaf(wgt, bf2f(u.y), acc.y);
    acc.z = fmaf(wgt, bf2f(u.z), acc.z);
    acc.w = fmaf(wgt, bf2f(u.w), acc.w);
  }
  float inv = den > 0.f ? 1.f/den : 0.f;
  const float4 bv = *(const float4*)&bias[h*DDIM + lane*4];
  acc.x = acc.x*inv + bv.x;
  acc.y = acc.y*inv + bv.y;
  acc.z = acc.z*inv + bv.z;
  acc.w = acc.w*inv + bv.w;
  *(float4*)&sm[h*DDIM + lane*4] = acc;
  __syncthreads();
  int t = threadIdx.x;
  out[(size_t)n*DDIM + t] =
      0.25f*((sm[t] + sm[DDIM + t]) + (sm[2*DDIM + t] + sm[3*DDIM + t]));
}

extern "C" void kernel_launch(void* const* d_in, const int* in_sizes, int n_in,
                              void* d_out, int out_size, void* d_ws, size_t ws_size,
                              hipStream_t stream) {
  const float* x   = (const float*)d_in[0];
  const int*   src = (const int*)d_in[1];
  const int*   dst = (const int*)d_in[2];
  const float* Wsrc[3] = {(const float*)d_in[3], (const float*)d_in[8],  (const float*)d_in[13]};
  const float* Wdst[3] = {(const float*)d_in[4], (const float*)d_in[9],  (const float*)d_in[14]};
  const float* al[3]   = {(const float*)d_in[5], (const float*)d_in[10], (const float*)d_in[15]};
  const float* ar[3]   = {(const float*)d_in[6], (const float*)d_in[11], (const float*)d_in[16]};
  const float* bb[3]   = {(const float*)d_in[7], (const float*)d_in[12], (const float*)d_in[17]};

  char* ws = (char*)d_ws;
  size_t off = 0;
  auto alloc = [&](size_t bytes) { void* p = ws + off; off += (bytes + 255) & ~255ull; return p; };
  unsigned short* fshB = (unsigned short*)alloc((size_t)NPAD*MCOLS*2);  // bf16 fs
  unsigned short* Ahi = (unsigned short*)alloc((size_t)NPAD*MCOLS*2);
  unsigned short* Alo = (unsigned short*)alloc((size_t)NPAD*MCOLS*2);
  unsigned short* Wth = (unsigned short*)alloc((size_t)MCOLS*MCOLS*2);
  float* elA  = (float*)alloc((size_t)NNODES*HEADS*4);
  float* elB  = (float*)alloc((size_t)NNODES*HEADS*4);
  float* erA  = (float*)alloc((size_t)NNODES*HEADS*4);
  float* erB  = (float*)alloc((size_t)NNODES*HEADS*4);
  float* wbuf = (float*)alloc((size_t)NEDGES*HEADS*4);
  float* WredB[3]; float* WalB[3];
  for (int l = 0; l < 3; ++l) {
    WredB[l] = (float*)alloc(1024*HEADS*4);
    WalB[l]  = (float*)alloc(1024*HEADS*4);
  }
  int* deg     = (int*)alloc((size_t)NNODES*4);
  int* row_ptr = (int*)alloc((size_t)(NNODES+1)*4);
  int* cursor  = (int*)alloc((size_t)NNODES*4);
  int* srcs    = (int*)alloc((size_t)NEDGES*4);
  int* dsts    = (int*)alloc((size_t)NEDGES*4);
  (void)ws_size; (void)in_sizes; (void)n_in; (void)out_size;

  // CSR build (graph identical across layers)
  k_zero<<<(NNODES+255)/256, 256, 0, stream>>>(deg, NNODES);
  k_hist<<<(NEDGES+255)/256, 256, 0, stream>>>(dst, deg, NEDGES);
  k_scan<<<1, 1024, 0, stream>>>(deg, row_ptr, cursor);
  k_fill<<<(NEDGES+255)/256, 256, 0, stream>>>(src, dst, cursor, srcs, dsts, NEDGES);

  const int Fin[3] = {512, 1024, 1024};
  for (int l = 0; l < 3; ++l) {
    k_fold<<<Fin[l], 256, 0, stream>>>(Wdst[l], ar[l], WredB[l], Fin[l]);
    k_fold<<<Fin[l], 256, 0, stream>>>(Wsrc[l], al[l], WalB[l], Fin[l]);
  }

  // layer 0 input prep
  k_cvt_a<<<(NPAD*512/4 + 255)/256, 256, 0, stream>>>(x, Ahi, Alo, NNODES*512, NPAD*512);
  k_eler0<<<NNODES, 256, 0, stream>>>(x, WalB[0], WredB[0], elA, erA);

  float* el_cur = elA; float* el_nxt = elB;
  float* er_cur = erA; float* er_nxt = erB;
  const int E4 = NEDGES*HEADS;
  for (int l = 0; l < 3; ++l) {
    int K = Fin[l];
    dim3 gw(MCOLS/32, K/32);
    k_cvt_w<<<gw, 256, 0, stream>>>(Wsrc[l], Wth, K);
    k_gemm_mfma<<<NBM*8, 256, 0, stream>>>(Ahi, Alo, Wth, fshB, K);
    k_wgt<<<(E4 + 255)/256, 256, 0, stream>>>(el_cur, er_cur, srcs, dsts, wbuf, E4);
    if (l < 2) {
      k_agg_f<<<NPAD, 256, 0, stream>>>(fshB, wbuf, row_ptr, srcs, bb[l],
                                        WalB[l+1], WredB[l+1], Ahi, Alo, el_nxt, er_nxt);
      float* t1 = el_cur; el_cur = el_nxt; el_nxt = t1;
      float* t2 = er_cur; er_cur = er_nxt; er_nxt = t2;
    } else {
      k_agg_out<<<NNODES, 256, 0, stream>>>(fshB, wbuf, row_ptr, srcs, bb[l],
                                            (float*)d_out);
    }
  }
}

// Round 8
// 804.108 us; speedup vs baseline: 1.0102x; 1.0102x over previous
//
#include <hip/hip_runtime.h>
#include <hip/hip_bf16.h>
#include <math.h>

#define NNODES 20000
#define NPAD   20480   // 160 * 128 (160 bm strips -> 20 per XCD)
#define NBM    160
#define NEDGES 320000
#define HEADS  4
#define DDIM   256
#define MCOLS  1024   // H*D

typedef __attribute__((ext_vector_type(8))) short short8;
typedef __attribute__((ext_vector_type(4))) float f32x4;

// bf16 helpers (bit-level, RNE)
__device__ __forceinline__ unsigned short f2bf(float f) {
  unsigned u = __float_as_uint(f);
  unsigned r = (u + 0x7fffu + ((u >> 16) & 1u)) >> 16;
  return (unsigned short)r;
}
__device__ __forceinline__ float bf2f(unsigned short h) {
  return __uint_as_float(((unsigned)h) << 16);
}
// unpack packed bf16 pair from a uint
__device__ __forceinline__ float blo(unsigned v) { return __uint_as_float(v << 16); }
__device__ __forceinline__ float bhi(unsigned v) { return __uint_as_float(v & 0xffff0000u); }

__device__ __forceinline__ void async_ld16(void* lds, const void* g) {
  __builtin_amdgcn_global_load_lds(
      (const __attribute__((address_space(1))) unsigned int*)g,
      (__attribute__((address_space(3))) unsigned int*)lds, 16, 0, 0);
}

// ---------------- CSR build (by dst) ----------------
__global__ void k_zero(int* deg, int n) {
  int i = blockIdx.x*blockDim.x + threadIdx.x;
  if (i < n) deg[i] = 0;
}
__global__ void k_hist(const int* __restrict__ dst, int* deg, int e) {
  int i = blockIdx.x*blockDim.x + threadIdx.x;
  if (i < e) atomicAdd(&deg[dst[i]], 1);
}
__global__ void k_scan(const int* __restrict__ deg, int* row_ptr, int* cursor) {
  __shared__ int sm[1024];
  int t = threadIdx.x;
  const int CH = 20;
  int base = t*CH;
  int s = 0;
  #pragma unroll
  for (int i = 0; i < CH; ++i) { int idx = base+i; if (idx < NNODES) s += deg[idx]; }
  int val = s;
  sm[t] = s; __syncthreads();
  for (int off = 1; off < 1024; off <<= 1) {
    int add = (t >= off) ? sm[t-off] : 0;
    __syncthreads();
    val += add; sm[t] = val;
    __syncthreads();
  }
  int run = val - s;
  for (int i = 0; i < CH; ++i) {
    int idx = base+i;
    if (idx < NNODES) { row_ptr[idx] = run; cursor[idx] = run; run += deg[idx]; }
  }
  if (t == 0) row_ptr[NNODES] = NEDGES;
}
__global__ void k_fill(const int* __restrict__ src, const int* __restrict__ dst,
                       int* cursor, int* srcs_sorted, int* dsts_sorted, int e) {
  int i = blockIdx.x*blockDim.x + threadIdx.x;
  if (i < e) {
    int d = dst[i];
    int pos = atomicAdd(&cursor[d], 1);
    srcs_sorted[pos] = src[i];
    dsts_sorted[pos] = d;
  }
}

// ---------------- all six folds in one launch ----------------
__device__ __forceinline__ void fold_body(const float* __restrict__ W,
                                          const float* __restrict__ v,
                                          float* __restrict__ F, int K, int bb) {
  int wave = threadIdx.x >> 6, lane = threadIdx.x & 63;
  int p = bb*4 + wave;            // p < K*4
  int k = p >> 2, h = p & 3;
  const float4 wv = *(const float4*)&W[(size_t)k*MCOLS + h*DDIM + lane*4];
  const float4 av = *(const float4*)&v[h*DDIM + lane*4];
  float s = wv.x*av.x + wv.y*av.y + wv.z*av.z + wv.w*av.w;
  for (int off = 32; off; off >>= 1) s += __shfl_xor(s, off);
  if (lane == 0) F[k*HEADS + h] = s;
}
__global__ __launch_bounds__(256) void k_fold_all(
    const float* Wd0, const float* ar0, float* F0,
    const float* Ws0, const float* al0, float* G0,
    const float* Wd1, const float* ar1, float* F1,
    const float* Ws1, const float* al1, float* G1,
    const float* Wd2, const float* ar2, float* F2,
    const float* Ws2, const float* al2, float* G2) {
  int b = blockIdx.x;
  if      (b < 512)  fold_body(Wd0, ar0, F0, 512,  b);
  else if (b < 1024) fold_body(Ws0, al0, G0, 512,  b - 512);
  else if (b < 2048) fold_body(Wd1, ar1, F1, 1024, b - 1024);
  else if (b < 3072) fold_body(Ws1, al1, G1, 1024, b - 2048);
  else if (b < 4096) fold_body(Wd2, ar2, F2, 1024, b - 3072);
  else               fold_body(Ws2, al2, G2, 1024, b - 4096);
}

// ---------------- layer-0 prep: split-bf16 A + el0/er0, one pass over x ----------
__global__ __launch_bounds__(256) void k_prep0(
    const float* __restrict__ x, const float* __restrict__ Wal,
    const float* __restrict__ Wred,
    unsigned short* __restrict__ hi, unsigned short* __restrict__ lo,
    float* __restrict__ el, float* __restrict__ er) {
  __shared__ float red_sm[4][8];
  int n = blockIdx.x, t = threadIdx.x;
  if (n >= NNODES) {
    *(ushort2*)&hi[(size_t)n*512 + 2*t] = (ushort2){0,0};
    *(ushort2*)&lo[(size_t)n*512 + 2*t] = (ushort2){0,0};
    return;
  }
  float2 xv = *(const float2*)&x[(size_t)n*512 + 2*t];
  ushort2 h2, l2;
  h2.x = f2bf(xv.x); l2.x = f2bf(xv.x - bf2f(h2.x));
  h2.y = f2bf(xv.y); l2.y = f2bf(xv.y - bf2f(h2.y));
  *(ushort2*)&hi[(size_t)n*512 + 2*t] = h2;
  *(ushort2*)&lo[(size_t)n*512 + 2*t] = l2;
  const float4 wa0 = *(const float4*)&Wal[(2*t)*4];
  const float4 wa1 = *(const float4*)&Wal[(2*t+1)*4];
  const float4 wr0 = *(const float4*)&Wred[(2*t)*4];
  const float4 wr1 = *(const float4*)&Wred[(2*t+1)*4];
  float p[8];
  p[0] = xv.x*wa0.x + xv.y*wa1.x;
  p[1] = xv.x*wa0.y + xv.y*wa1.y;
  p[2] = xv.x*wa0.z + xv.y*wa1.z;
  p[3] = xv.x*wa0.w + xv.y*wa1.w;
  p[4] = xv.x*wr0.x + xv.y*wr1.x;
  p[5] = xv.x*wr0.y + xv.y*wr1.y;
  p[6] = xv.x*wr0.z + xv.y*wr1.z;
  p[7] = xv.x*wr0.w + xv.y*wr1.w;
  for (int off = 32; off; off >>= 1)
    #pragma unroll
    for (int j = 0; j < 8; ++j) p[j] += __shfl_xor(p[j], off);
  if ((t & 63) == 0)
    #pragma unroll
    for (int j = 0; j < 8; ++j) red_sm[t >> 6][j] = p[j];
  __syncthreads();
  if (t < 8) {
    float v = (red_sm[0][t] + red_sm[1][t]) + (red_sm[2][t] + red_sm[3][t]);
    if (t < 4) el[n*HEADS + t] = v;
    else       er[n*HEADS + (t-4)] = v;
  }
}

// ---------------- combined: W transpose->bf16 + per-edge softmax weights ----------
__global__ __launch_bounds__(256) void k_cvtw_wgt(
    const float* __restrict__ W, unsigned short* __restrict__ Th, int K,
    const float* __restrict__ el, const float* __restrict__ er,
    const int* __restrict__ srcs, const int* __restrict__ dsts,
    float* __restrict__ wb, int e4) {
  int b = blockIdx.x;
  if (b < K) {   // transpose part: K blocks (32 n-tiles x K/32 k-tiles)
    __shared__ float sm[32][33];
    int n0 = (b & 31)*32, k0 = (b >> 5)*32;
    int t = threadIdx.x;
    int r = t >> 3, c4 = (t & 7)*4;
    *(float4*)&sm[r][c4] = *(const float4*)&W[(size_t)(k0 + r)*MCOLS + n0 + c4];
    __syncthreads();
    ushort4 h;
    h.x = f2bf(sm[c4+0][r]);
    h.y = f2bf(sm[c4+1][r]);
    h.z = f2bf(sm[c4+2][r]);
    h.w = f2bf(sm[c4+3][r]);
    *(ushort4*)&Th[(size_t)(n0 + r)*K + k0 + c4] = h;
  } else {
    int i = (b - K)*256 + threadIdx.x;
    if (i < e4) {
      int pos = i >> 2, h = i & 3;
      float v = el[srcs[pos]*HEADS + h] + er[dsts[pos]*HEADS + h];
      v = v >= 0.f ? v : 0.2f*v;
      wb[i] = __expf(v);
    }
  }
}

// ---------------- MFMA GEMM (split-2: Ah*Bh + Al*Bh), bf16 output ----------------
// XCD-aware swizzle (r6): each XCD owns 20 exclusive bm strips.
__global__ __launch_bounds__(256, 3) void k_gemm_mfma(
    const unsigned short* __restrict__ Ah, const unsigned short* __restrict__ Al,
    const unsigned short* __restrict__ Bh,
    unsigned short* __restrict__ Fh, int K) {
  __shared__ short sAh[128*32], sAl[128*32], sBh[128*32];
  const int t = threadIdx.x;
  const int w = t >> 6, l = t & 63;
  const int b = blockIdx.x;
  const int xcd = b & 7, kk = b >> 3;
  const int bm = xcd*20 + (kk >> 3), bn = kk & 7;
  const int m0 = (w >> 1) * 64, n0 = (w & 1) * 64;

  f32x4 acc[4][4];
  #pragma unroll
  for (int i = 0; i < 4; ++i)
    #pragma unroll
    for (int j = 0; j < 4; ++j) acc[i][j] = (f32x4){0.f, 0.f, 0.f, 0.f};

  const int srow = t >> 2, koct = (t & 3) * 8;
  const size_t r64 = (size_t)64 * K;
  const unsigned short* gAh = Ah + (size_t)(bm*128 + srow)*K + koct;
  const unsigned short* gAl = Al + (size_t)(bm*128 + srow)*K + koct;
  const unsigned short* gBh = Bh + (size_t)(bn*128 + srow)*K + koct;
  char* lAh = (char*)sAh + w*1024;
  char* lAl = (char*)sAl + w*1024;
  char* lBh = (char*)sBh + w*1024;

  const int fr = l & 15, fq = l >> 4;

  for (int k0 = 0; k0 < K; k0 += 32) {
    async_ld16(lAh,        gAh + k0);
    async_ld16(lAh + 4096, gAh + k0 + r64);
    async_ld16(lAl,        gAl + k0);
    async_ld16(lAl + 4096, gAl + k0 + r64);
    async_ld16(lBh,        gBh + k0);
    async_ld16(lBh + 4096, gBh + k0 + r64);
    __syncthreads();

    short8 bhv[4];
    #pragma unroll
    for (int nt = 0; nt < 4; ++nt)
      bhv[nt] = *(const short8*)&sBh[(n0 + nt*16 + fr)*32 + fq*8];
    #pragma unroll
    for (int mt = 0; mt < 4; ++mt) {
      int off = (m0 + mt*16 + fr)*32 + fq*8;
      short8 ah = *(const short8*)&sAh[off];
      short8 al = *(const short8*)&sAl[off];
      #pragma unroll
      for (int nt = 0; nt < 4; ++nt) {
        acc[mt][nt] = __builtin_amdgcn_mfma_f32_16x16x32_bf16(ah, bhv[nt], acc[mt][nt], 0, 0, 0);
        acc[mt][nt] = __builtin_amdgcn_mfma_f32_16x16x32_bf16(al, bhv[nt], acc[mt][nt], 0, 0, 0);
      }
    }
    __syncthreads();
  }

  #pragma unroll
  for (int mt = 0; mt < 4; ++mt)
    #pragma unroll
    for (int nt = 0; nt < 4; ++nt) {
      size_t base = (size_t)(bm*128 + m0 + mt*16 + fq*4)*MCOLS + bn*128 + n0 + nt*16 + fr;
      Fh[base          ] = f2bf(acc[mt][nt][0]);
      Fh[base + MCOLS  ] = f2bf(acc[mt][nt][1]);
      Fh[base + 2*MCOLS] = f2bf(acc[mt][nt][2]);
      Fh[base + 3*MCOLS] = f2bf(acc[mt][nt][3]);
    }
}

// ---------------- fused aggregation (layers 0,1): 128 thr, dwordx4 gather --------
// wave w -> heads {2w, 2w+1}; lanes 0-31 head 2w, 32-63 head 2w+1; 8 dims/lane.
__global__ __launch_bounds__(128) void k_agg_f(
    const unsigned short* __restrict__ fsh, const float* __restrict__ wbuf,
    const int* __restrict__ row_ptr, const int* __restrict__ srcs,
    const float* __restrict__ bias,
    const float* __restrict__ WalN, const float* __restrict__ WredN,
    unsigned short* __restrict__ Ahi, unsigned short* __restrict__ Alo,
    float* __restrict__ el_next, float* __restrict__ er_next) {
  __shared__ float red_sm[2][8];
  int n = blockIdx.x;
  int t = threadIdx.x;
  int w = t >> 6, lane = t & 63;
  int half = lane >> 5, lam = lane & 31;
  int head = w*2 + half;
  int k0 = head*DDIM + lam*8;
  if (n >= NNODES) {
    uint4 z = {0,0,0,0};
    *(uint4*)&Ahi[(size_t)n*MCOLS + k0] = z;
    *(uint4*)&Alo[(size_t)n*MCOLS + k0] = z;
    return;
  }
  int beg = row_ptr[n], end = row_ptr[n+1];
  float den = 0.f;
  float ac[8];
  #pragma unroll
  for (int j = 0; j < 8; ++j) ac[j] = 0.f;
  const char* fbyte = (const char*)fsh;
  const unsigned tb = (unsigned)(k0*2);
  int i = beg;
  for (; i + 3 < end; i += 4) {
    int s0 = srcs[i], s1 = srcs[i+1], s2 = srcs[i+2], s3 = srcs[i+3];
    float2 wv0 = *(const float2*)&wbuf[(size_t)(i  )*HEADS + w*2];
    float2 wv1 = *(const float2*)&wbuf[(size_t)(i+1)*HEADS + w*2];
    float2 wv2 = *(const float2*)&wbuf[(size_t)(i+2)*HEADS + w*2];
    float2 wv3 = *(const float2*)&wbuf[(size_t)(i+3)*HEADS + w*2];
    const uint4 u0 = *(const uint4*)(fbyte + ((unsigned)s0*2048u + tb));
    const uint4 u1 = *(const uint4*)(fbyte + ((unsigned)s1*2048u + tb));
    const uint4 u2 = *(const uint4*)(fbyte + ((unsigned)s2*2048u + tb));
    const uint4 u3 = *(const uint4*)(fbyte + ((unsigned)s3*2048u + tb));
    float w0 = half ? wv0.y : wv0.x;
    float w1 = half ? wv1.y : wv1.x;
    float w2 = half ? wv2.y : wv2.x;
    float w3 = half ? wv3.y : wv3.x;
    den += (w0 + w1) + (w2 + w3);
    ac[0] = fmaf(w0, blo(u0.x), fmaf(w1, blo(u1.x), fmaf(w2, blo(u2.x), fmaf(w3, blo(u3.x), ac[0]))));
    ac[1] = fmaf(w0, bhi(u0.x), fmaf(w1, bhi(u1.x), fmaf(w2, bhi(u2.x), fmaf(w3, bhi(u3.x), ac[1]))));
    ac[2] = fmaf(w0, blo(u0.y), fmaf(w1, blo(u1.y), fmaf(w2, blo(u2.y), fmaf(w3, blo(u3.y), ac[2]))));
    ac[3] = fmaf(w0, bhi(u0.y), fmaf(w1, bhi(u1.y), fmaf(w2, bhi(u2.y), fmaf(w3, bhi(u3.y), ac[3]))));
    ac[4] = fmaf(w0, blo(u0.z), fmaf(w1, blo(u1.z), fmaf(w2, blo(u2.z), fmaf(w3, blo(u3.z), ac[4]))));
    ac[5] = fmaf(w0, bhi(u0.z), fmaf(w1, bhi(u1.z), fmaf(w2, bhi(u2.z), fmaf(w3, bhi(u3.z), ac[5]))));
    ac[6] = fmaf(w0, blo(u0.w), fmaf(w1, blo(u1.w), fmaf(w2, blo(u2.w), fmaf(w3, blo(u3.w), ac[6]))));
    ac[7] = fmaf(w0, bhi(u0.w), fmaf(w1, bhi(u1.w), fmaf(w2, bhi(u2.w), fmaf(w3, bhi(u3.w), ac[7]))));
  }
  for (; i < end; ++i) {
    int s = srcs[i];
    float2 wv = *(const float2*)&wbuf[(size_t)i*HEADS + w*2];
    float wgt = half ? wv.y : wv.x;
    const uint4 u = *(const uint4*)(fbyte + ((unsigned)s*2048u + tb));
    den += wgt;
    ac[0] = fmaf(wgt, blo(u.x), ac[0]);
    ac[1] = fmaf(wgt, bhi(u.x), ac[1]);
    ac[2] = fmaf(wgt, blo(u.y), ac[2]);
    ac[3] = fmaf(wgt, bhi(u.y), ac[3]);
    ac[4] = fmaf(wgt, blo(u.z), ac[4]);
    ac[5] = fmaf(wgt, bhi(u.z), ac[5]);
    ac[6] = fmaf(wgt, blo(u.w), ac[6]);
    ac[7] = fmaf(wgt, bhi(u.w), ac[7]);
  }
  float inv = den > 0.f ? 1.f/den : 0.f;
  const float4 bv0 = *(const float4*)&bias[k0];
  const float4 bv1 = *(const float4*)&bias[k0 + 4];
  float o[8];
  o[0] = fmaxf(ac[0]*inv + bv0.x, 0.f);
  o[1] = fmaxf(ac[1]*inv + bv0.y, 0.f);
  o[2] = fmaxf(ac[2]*inv + bv0.z, 0.f);
  o[3] = fmaxf(ac[3]*inv + bv0.w, 0.f);
  o[4] = fmaxf(ac[4]*inv + bv1.x, 0.f);
  o[5] = fmaxf(ac[5]*inv + bv1.y, 0.f);
  o[6] = fmaxf(ac[6]*inv + bv1.z, 0.f);
  o[7] = fmaxf(ac[7]*inv + bv1.w, 0.f);
  // split-bf16 emit (packed 16B stores)
  uint4 hp, lp;
  unsigned h0, h1;
  h0 = f2bf(o[0]); h1 = f2bf(o[1]); hp.x = h0 | (h1 << 16);
  lp.x = (unsigned)f2bf(o[0] - bf2f((unsigned short)h0)) |
         ((unsigned)f2bf(o[1] - bf2f((unsigned short)h1)) << 16);
  h0 = f2bf(o[2]); h1 = f2bf(o[3]); hp.y = h0 | (h1 << 16);
  lp.y = (unsigned)f2bf(o[2] - bf2f((unsigned short)h0)) |
         ((unsigned)f2bf(o[3] - bf2f((unsigned short)h1)) << 16);
  h0 = f2bf(o[4]); h1 = f2bf(o[5]); hp.z = h0 | (h1 << 16);
  lp.z = (unsigned)f2bf(o[4] - bf2f((unsigned short)h0)) |
         ((unsigned)f2bf(o[5] - bf2f((unsigned short)h1)) << 16);
  h0 = f2bf(o[6]); h1 = f2bf(o[7]); hp.w = h0 | (h1 << 16);
  lp.w = (unsigned)f2bf(o[6] - bf2f((unsigned short)h0)) |
         ((unsigned)f2bf(o[7] - bf2f((unsigned short)h1)) << 16);
  *(uint4*)&Ahi[(size_t)n*MCOLS + k0] = hp;
  *(uint4*)&Alo[(size_t)n*MCOLS + k0] = lp;
  // el/er next: p[h2] partials over this thread's 8 dims
  float p[8];
  #pragma unroll
  for (int j = 0; j < 8; ++j) p[j] = 0.f;
  #pragma unroll
  for (int j = 0; j < 8; ++j) {
    const float4 wa = *(const float4*)&WalN[(k0+j)*HEADS];
    const float4 wr = *(const float4*)&WredN[(k0+j)*HEADS];
    p[0] = fmaf(o[j], wa.x, p[0]);
    p[1] = fmaf(o[j], wa.y, p[1]);
    p[2] = fmaf(o[j], wa.z, p[2]);
    p[3] = fmaf(o[j], wa.w, p[3]);
    p[4] = fmaf(o[j], wr.x, p[4]);
    p[5] = fmaf(o[j], wr.y, p[5]);
    p[6] = fmaf(o[j], wr.z, p[6]);
    p[7] = fmaf(o[j], wr.w, p[7]);
  }
  for (int off = 32; off; off >>= 1)
    #pragma unroll
    for (int j = 0; j < 8; ++j) p[j] += __shfl_xor(p[j], off);
  if (lane == 0)
    #pragma unroll
    for (int j = 0; j < 8; ++j) red_sm[w][j] = p[j];
  __syncthreads();
  if (t < 8) {
    float v = red_sm[0][t] + red_sm[1][t];
    if (t < 4) el_next[n*HEADS + t] = v;
    else       er_next[n*HEADS + (t-4)] = v;
  }
}

// ---------------- final aggregation (layer 2): 128 thr, dwordx4, head mean -------
__global__ __launch_bounds__(128) void k_agg_out(
    const unsigned short* __restrict__ fsh, const float* __restrict__ wbuf,
    const int* __restrict__ row_ptr, const int* __restrict__ srcs,
    const float* __restrict__ bias, float* __restrict__ out) {
  __shared__ float sm[HEADS*DDIM];
  int n = blockIdx.x;
  int t = threadIdx.x;
  int w = t >> 6, lane = t & 63;
  int half = lane >> 5, lam = lane & 31;
  int head = w*2 + half;
  int k0 = head*DDIM + lam*8;
  int beg = row_ptr[n], end = row_ptr[n+1];
  float den = 0.f;
  float ac[8];
  #pragma unroll
  for (int j = 0; j < 8; ++j) ac[j] = 0.f;
  const char* fbyte = (const char*)fsh;
  const unsigned tb = (unsigned)(k0*2);
  int i = beg;
  for (; i + 3 < end; i += 4) {
    int s0 = srcs[i], s1 = srcs[i+1], s2 = srcs[i+2], s3 = srcs[i+3];
    float2 wv0 = *(const float2*)&wbuf[(size_t)(i  )*HEADS + w*2];
    float2 wv1 = *(const float2*)&wbuf[(size_t)(i+1)*HEADS + w*2];
    float2 wv2 = *(const float2*)&wbuf[(size_t)(i+2)*HEADS + w*2];
    float2 wv3 = *(const float2*)&wbuf[(size_t)(i+3)*HEADS + w*2];
    const uint4 u0 = *(const uint4*)(fbyte + ((unsigned)s0*2048u + tb));
    const uint4 u1 = *(const uint4*)(fbyte + ((unsigned)s1*2048u + tb));
    const uint4 u2 = *(const uint4*)(fbyte + ((unsigned)s2*2048u + tb));
    const uint4 u3 = *(const uint4*)(fbyte + ((unsigned)s3*2048u + tb));
    float w0 = half ? wv0.y : wv0.x;
    float w1 = half ? wv1.y : wv1.x;
    float w2 = half ? wv2.y : wv2.x;
    float w3 = half ? wv3.y : wv3.x;
    den += (w0 + w1) + (w2 + w3);
    ac[0] = fmaf(w0, blo(u0.x), fmaf(w1, blo(u1.x), fmaf(w2, blo(u2.x), fmaf(w3, blo(u3.x), ac[0]))));
    ac[1] = fmaf(w0, bhi(u0.x), fmaf(w1, bhi(u1.x), fmaf(w2, bhi(u2.x), fmaf(w3, bhi(u3.x), ac[1]))));
    ac[2] = fmaf(w0, blo(u0.y), fmaf(w1, blo(u1.y), fmaf(w2, blo(u2.y), fmaf(w3, blo(u3.y), ac[2]))));
    ac[3] = fmaf(w0, bhi(u0.y), fmaf(w1, bhi(u1.y), fmaf(w2, bhi(u2.y), fmaf(w3, bhi(u3.y), ac[3]))));
    ac[4] = fmaf(w0, blo(u0.z), fmaf(w1, blo(u1.z), fmaf(w2, blo(u2.z), fmaf(w3, blo(u3.z), ac[4]))));
    ac[5] = fmaf(w0, bhi(u0.z), fmaf(w1, bhi(u1.z), fmaf(w2, bhi(u2.z), fmaf(w3, bhi(u3.z), ac[5]))));
    ac[6] = fmaf(w0, blo(u0.w), fmaf(w1, blo(u1.w), fmaf(w2, blo(u2.w), fmaf(w3, blo(u3.w), ac[6]))));
    ac[7] = fmaf(w0, bhi(u0.w), fmaf(w1, bhi(u1.w), fmaf(w2, bhi(u2.w), fmaf(w3, bhi(u3.w), ac[7]))));
  }
  for (; i < end; ++i) {
    int s = srcs[i];
    float2 wv = *(const float2*)&wbuf[(size_t)i*HEADS + w*2];
    float wgt = half ? wv.y : wv.x;
    const uint4 u = *(const uint4*)(fbyte + ((unsigned)s*2048u + tb));
    den += wgt;
    ac[0] = fmaf(wgt, blo(u.x), ac[0]);
    ac[1] = fmaf(wgt, bhi(u.x), ac[1]);
    ac[2] = fmaf(wgt, blo(u.y), ac[2]);
    ac[3] = fmaf(wgt, bhi(u.y), ac[3]);
    ac[4] = fmaf(wgt, blo(u.z), ac[4]);
    ac[5] = fmaf(wgt, bhi(u.z), ac[5]);
    ac[6] = fmaf(wgt, blo(u.w), ac[6]);
    ac[7] = fmaf(wgt, bhi(u.w), ac[7]);
  }
  float inv = den > 0.f ? 1.f/den : 0.f;
  const float4 bv0 = *(const float4*)&bias[k0];
  const float4 bv1 = *(const float4*)&bias[k0 + 4];
  sm[k0+0] = ac[0]*inv + bv0.x;
  sm[k0+1] = ac[1]*inv + bv0.y;
  sm[k0+2] = ac[2]*inv + bv0.z;
  sm[k0+3] = ac[3]*inv + bv0.w;
  sm[k0+4] = ac[4]*inv + bv1.x;
  sm[k0+5] = ac[5]*inv + bv1.y;
  sm[k0+6] = ac[6]*inv + bv1.z;
  sm[k0+7] = ac[7]*inv + bv1.w;
  __syncthreads();
  #pragma unroll
  for (int rep = 0; rep < 2; ++rep) {
    int d = t + rep*128;
    out[(size_t)n*DDIM + d] =
        0.25f*((sm[d] + sm[DDIM + d]) + (sm[2*DDIM + d] + sm[3*DDIM + d]));
  }
}

extern "C" void kernel_launch(void* const* d_in, const int* in_sizes, int n_in,
                              void* d_out, int out_size, void* d_ws, size_t ws_size,
                              hipStream_t stream) {
  const float* x   = (const float*)d_in[0];
  const int*   src = (const int*)d_in[1];
  const int*   dst = (const int*)d_in[2];
  const float* Wsrc[3] = {(const float*)d_in[3], (const float*)d_in[8],  (const float*)d_in[13]};
  const float* Wdst[3] = {(const float*)d_in[4], (const float*)d_in[9],  (const float*)d_in[14]};
  const float* al[3]   = {(const float*)d_in[5], (const float*)d_in[10], (const float*)d_in[15]};
  const float* ar[3]   = {(const float*)d_in[6], (const float*)d_in[11], (const float*)d_in[16]};
  const float* bb[3]   = {(const float*)d_in[7], (const float*)d_in[12], (const float*)d_in[17]};

  char* ws = (char*)d_ws;
  size_t off = 0;
  auto alloc = [&](size_t bytes) { void* p = ws + off; off += (bytes + 255) & ~255ull; return p; };
  unsigned short* fshB = (unsigned short*)alloc((size_t)NPAD*MCOLS*2);  // bf16 fs
  unsigned short* Ahi = (unsigned short*)alloc((size_t)NPAD*MCOLS*2);
  unsigned short* Alo = (unsigned short*)alloc((size_t)NPAD*MCOLS*2);
  unsigned short* Wth = (unsigned short*)alloc((size_t)MCOLS*MCOLS*2);
  float* elA  = (float*)alloc((size_t)NNODES*HEADS*4);
  float* elB  = (float*)alloc((size_t)NNODES*HEADS*4);
  float* erA  = (float*)alloc((size_t)NNODES*HEADS*4);
  float* erB  = (float*)alloc((size_t)NNODES*HEADS*4);
  float* wbuf = (float*)alloc((size_t)NEDGES*HEADS*4);
  float* WredB[3]; float* WalB[3];
  for (int l = 0; l < 3; ++l) {
    WredB[l] = (float*)alloc(1024*HEADS*4);
    WalB[l]  = (float*)alloc(1024*HEADS*4);
  }
  int* deg     = (int*)alloc((size_t)NNODES*4);
  int* row_ptr = (int*)alloc((size_t)(NNODES+1)*4);
  int* cursor  = (int*)alloc((size_t)NNODES*4);
  int* srcs    = (int*)alloc((size_t)NEDGES*4);
  int* dsts    = (int*)alloc((size_t)NEDGES*4);
  (void)ws_size; (void)in_sizes; (void)n_in; (void)out_size;

  // CSR build (graph identical across layers)
  k_zero<<<(NNODES+255)/256, 256, 0, stream>>>(deg, NNODES);
  k_hist<<<(NEDGES+255)/256, 256, 0, stream>>>(dst, deg, NEDGES);
  k_scan<<<1, 1024, 0, stream>>>(deg, row_ptr, cursor);
  k_fill<<<(NEDGES+255)/256, 256, 0, stream>>>(src, dst, cursor, srcs, dsts, NEDGES);

  // all folds in one launch
  k_fold_all<<<5120, 256, 0, stream>>>(
      Wdst[0], ar[0], WredB[0], Wsrc[0], al[0], WalB[0],
      Wdst[1], ar[1], WredB[1], Wsrc[1], al[1], WalB[1],
      Wdst[2], ar[2], WredB[2], Wsrc[2], al[2], WalB[2]);

  // layer-0 prep: split-bf16 A + el0/er0 in one pass
  k_prep0<<<NPAD, 256, 0, stream>>>(x, WalB[0], WredB[0], Ahi, Alo, elA, erA);

  float* el_cur = elA; float* el_nxt = elB;
  float* er_cur = erA; float* er_nxt = erB;
  const int Fin[3] = {512, 1024, 1024};
  const int E4 = NEDGES*HEADS;
  for (int l = 0; l < 3; ++l) {
    int K = Fin[l];
    k_cvtw_wgt<<<K + (E4 + 255)/256, 256, 0, stream>>>(
        Wsrc[l], Wth, K, el_cur, er_cur, srcs, dsts, wbuf, E4);
    k_gemm_mfma<<<NBM*8, 256, 0, stream>>>(Ahi, Alo, Wth, fshB, K);
    if (l < 2) {
      k_agg_f<<<NPAD, 128, 0, stream>>>(fshB, wbuf, row_ptr, srcs, bb[l],
                                        WalB[l+1], WredB[l+1], Ahi, Alo, el_nxt, er_nxt);
      float* t1 = el_cur; el_cur = el_nxt; el_nxt = t1;
      float* t2 = er_cur; er_cur = er_nxt; er_nxt = t2;
    } else {
      k_agg_out<<<NNODES, 128, 0, stream>>>(fshB, wbuf, row_ptr, srcs, bb[l],
                                            (float*)d_out);
    }
  }
}